// Round 12
// baseline (312.549 us; speedup 1.0000x reference)
//
#include <hip/hip_runtime.h>
#include <hip/hip_bf16.h>

// PINN fused forward+jvp^2 via split-fp16 MFMA.
// R21 = R19 (234.5us: BS=16, 512thr, 2 blocks/CU, 16x16x32 split-fp16,
// staged A in STG layers, vb-split, setprio, MFMA tail, no dead guards,
// full unroll) + three cuts:
//  (1) L3 half-staging: Ah[4] prefetched one kt ahead (Al inline). L3 is
//      41% of MFMA work and was the only fully-inline-load layer.
//      +16 VGPR -> ~124 incl. AGPR, under the 128 2-block budget.
//  (2) Dual-matrix tail: A2 = A - 1*bvec^T packed as tiles 7-13 of C6.
//      Wave w computes U0 (tile w) AND U1 (tile 7+w): u1 = U + DT*F@A2^T
//      == u0 - DT*cb. Removes cbv broadcast + 1 barrier + u1 VALU; all
//      7 tail waves get 2 tiles. +84 MFMAs (~0.4% matrix time).
//  (3) U kept in registers across the tail (the Umf LDS round-trip was
//      same-lane write->read; pure waste).
// R20 lesson: epilogue hoist neutral -- cross-block masking already
// covers the inter-barrier VALU window. Reverted.

#define NSAMP 65536
#define Q     100
#define DTC   0.8f
#define BS    16
#define THREADS 512
#define STR   520          // LDS plane stride (halves); MUST be mult of 8

typedef _Float16 h8 __attribute__((ext_vector_type(8)));
typedef _Float16 h4 __attribute__((ext_vector_type(4)));
typedef float    f4 __attribute__((ext_vector_type(4)));

// ---- packed fragment-ready weight geometry (halves) ----
// per layer: MT * KT * 512 halves (frag = 64 lanes x 8 halves)
// L1: MT=4,  KT=1  ->   2048
// L2: MT=14, KT=2  ->  14336
// L3: MT=32, KT=7  -> 114688
// L4: MT=14, KT=16 -> 114688
// L5: MT=7,  KT=7  ->  25088
// L6 dual tail: MT=14, KT=4 -> 28672
//    tiles 0-6 : Aext rows 0..111  (A rows 0-99, 100-111 zero)
//    tiles 7-13: A2 = A - 1*bvec^T rows 0..99 (100-111 zero)
#define SW 299520
#define C1 0
#define C2 2048
#define C3 16384
#define C4 131072
#define C5 245760
#define C6 270848
#define BP1 0
#define BP2 64
#define BP3 288
#define BP4 800
#define BP5 1024
#define BPTOT 1136
#define WS_BIAS_BYTE_OFF (SW*2*2)

__device__ __forceinline__ float fast_tanh(float z) {
    float az = fabsf(z);
    float e  = __expf(-2.0f * az);
    float r  = __builtin_amdgcn_rcpf(1.0f + e);
    float t  = (1.0f - e) * r;
    return copysignf(t, z);
}

struct Split { _Float16 hi, lo; };
__device__ __forceinline__ Split split16(float v) {
    Split s;
    s.hi = (_Float16)v;
    s.lo = (_Float16)(v - (float)s.hi);
    return s;
}

// ---------------- pre-pass: split/pad/PACK weights + biases + dual tail mats ----------------
__global__ __launch_bounds__(256) void prepass(
    const float* __restrict__ W1, const float* __restrict__ b1,
    const float* __restrict__ W2, const float* __restrict__ b2,
    const float* __restrict__ W3, const float* __restrict__ b3,
    const float* __restrict__ W4, const float* __restrict__ b4,
    const float* __restrict__ W5, const float* __restrict__ b5,
    const float* __restrict__ Amat, const float* __restrict__ bvec,
    _Float16* __restrict__ whi, float* __restrict__ biasP)
{
    int idx = blockIdx.x * 256 + threadIdx.x;
    _Float16* wlo = whi + SW;
    if (idx < SW) {
        int base, KT, K, FOUT; const float* W; bool ext = false;
        if      (idx < C2) { base=C1; KT=1;  K=20;  FOUT=50;  W=W1; }
        else if (idx < C3) { base=C2; KT=2;  K=50;  FOUT=200; W=W2; }
        else if (idx < C4) { base=C3; KT=7;  K=200; FOUT=500; W=W3; }
        else if (idx < C5) { base=C4; KT=16; K=500; FOUT=200; W=W4; }
        else if (idx < C6) { base=C5; KT=7;  K=200; FOUT=100; W=W5; }
        else               { base=C6; KT=4;  K=100; FOUT=224; W=Amat; ext = true; }
        int r    = idx - base;
        int frag = r >> 9;
        int f    = r & 511;
        int lane = f >> 3;
        int e    = f & 7;
        int colS = lane & 15;
        int kg   = lane >> 4;
        int mt   = frag / KT;
        int kt   = frag - mt * KT;
        int o = mt * 16 + colS;
        int k = kt * 32 + kg * 8 + e;
        float v = 0.f;
        if (o < FOUT && k < K) {
            if (!ext) {
                v = W[o * K + k];
            } else {
                if (o < 100)                    v = Amat[o * 100 + k];
                else if (o >= 112 && o < 212)   v = Amat[(o - 112) * 100 + k] - bvec[k];
                // else rows 100-111 / 212-223: zero pad
            }
        }
        Split sp = split16(v);
        whi[idx] = sp.hi; wlo[idx] = sp.lo;
    } else if (idx < SW + BPTOT) {
        int b = idx - SW;
        const float* src; int FOUT; int o;
        if      (b < BP2)  { src=b1; FOUT=50;  o=b;        }
        else if (b < BP3)  { src=b2; FOUT=200; o=b-BP2;    }
        else if (b < BP4)  { src=b3; FOUT=500; o=b-BP3;    }
        else if (b < BP5)  { src=b4; FOUT=200; o=b-BP4;    }
        else               { src=b5; FOUT=100; o=b-BP5;    }
        biasP[b] = (o < FOUT) ? src[o] : 0.f;
    }
}

// ---------------- one MFMA layer ----------------
// Planes (LDS, stride STR halves): vhi, vlo (split v-state), dhi, ddh (fp16 d/dd).
// B-frag: lane l -> col = l&15 (sample), k0 = (l>>4)*8 + kt*32.
// A-frag: PACKED: base + (mt*KT + kt)*512 + lane*8  -> coalesced 1KB load.
// C/D: col(lane&15)=sample, row((lane>>4)*4+reg)=output neuron.
// STG path (NMT<=2): full Ah+Al staged 1-ahead.
// L3 path (NMT=4): Ah staged 1-ahead, Al inline (register budget).
// Epilogue: no FOUT guard (zero-padded weights make padded outputs 0).
template<int KP, int MTILES, int NMT, int NWACT, int FOUT, bool TANH>
__device__ __forceinline__ void layer_mfma(
    const _Float16* __restrict__ whi, const _Float16* __restrict__ wlo,
    int wcoff, const float* __restrict__ biasP,
    _Float16* vhi, _Float16* vlo, _Float16* dhi, _Float16* ddh,
    int lane, int wv)
{
    constexpr int KT  = KP / 32;
    constexpr bool STG = (NMT <= 2);
    static_assert(MTILES == NMT * NWACT, "exact tiling expected");
    const int colS = lane & 15;
    const int kg   = lane >> 4;
    const bool act = (wv < NWACT);

    f4 accva[NMT], accvb[STG ? NMT : 1], accd[NMT], accdd[NMT];

    if (act) {
#pragma unroll
        for (int i = 0; i < NMT; ++i) {
            accva[i] = (f4){0.f, 0.f, 0.f, 0.f};
            accd[i]  = (f4){0.f, 0.f, 0.f, 0.f};
            accdd[i] = (f4){0.f, 0.f, 0.f, 0.f};
        }
        if constexpr (STG) {
#pragma unroll
            for (int i = 0; i < NMT; ++i)
                accvb[i] = (f4){0.f, 0.f, 0.f, 0.f};
        }

        const int boff = colS * STR + kg * 8;

        unsigned woff[NMT];
#pragma unroll
        for (int i = 0; i < NMT; ++i)
            woff[i] = (unsigned)(wcoff + ((wv + NWACT * i) * KT) * 512 + lane * 8);

        if constexpr (STG) {
            // ---- fully-staged A-load path ----
            h8 Ah[NMT], Al[NMT], Ah2[NMT], Al2[NMT];
#pragma unroll
            for (int i = 0; i < NMT; ++i) {
                Ah[i] = *(const h8*)(whi + woff[i]);
                Al[i] = *(const h8*)(wlo + woff[i]);
            }
#pragma unroll
            for (int kt = 0; kt < KT; ++kt) {
                if (kt + 1 < KT) {
                    const int kwb = (kt + 1) * 512;
#pragma unroll
                    for (int i = 0; i < NMT; ++i) {
                        Ah2[i] = *(const h8*)(whi + woff[i] + kwb);
                        Al2[i] = *(const h8*)(wlo + woff[i] + kwb);
                    }
                }
                const int kb = kt * 32;
                h8 Bvh = *(const h8*)(vhi + boff + kb);
                h8 Bvl = *(const h8*)(vlo + boff + kb);
                h8 Bdh = *(const h8*)(dhi + boff + kb);
                h8 Bdd = *(const h8*)(ddh + boff + kb);
                __builtin_amdgcn_s_setprio(1);
#pragma unroll
                for (int i = 0; i < NMT; ++i) {
                    accva[i] = __builtin_amdgcn_mfma_f32_16x16x32_f16(Ah[i], Bvh, accva[i], 0, 0, 0);
                    accvb[i] = __builtin_amdgcn_mfma_f32_16x16x32_f16(Ah[i], Bvl, accvb[i], 0, 0, 0);
                    accvb[i] = __builtin_amdgcn_mfma_f32_16x16x32_f16(Al[i], Bvh, accvb[i], 0, 0, 0);
                    accd[i]  = __builtin_amdgcn_mfma_f32_16x16x32_f16(Ah[i], Bdh, accd[i],  0, 0, 0);
                    accdd[i] = __builtin_amdgcn_mfma_f32_16x16x32_f16(Ah[i], Bdd, accdd[i], 0, 0, 0);
                }
                __builtin_amdgcn_s_setprio(0);
                if (kt + 1 < KT) {
#pragma unroll
                    for (int i = 0; i < NMT; ++i) { Ah[i] = Ah2[i]; Al[i] = Al2[i]; }
                }
            }
        } else {
            // ---- L3: Ah staged 1-ahead, Al inline (register-tight) ----
            h8 Ah[NMT], Ah2[NMT];
#pragma unroll
            for (int i = 0; i < NMT; ++i)
                Ah[i] = *(const h8*)(whi + woff[i]);
#pragma unroll
            for (int kt = 0; kt < KT; ++kt) {
                if (kt + 1 < KT) {
                    const int kwb = (kt + 1) * 512;
#pragma unroll
                    for (int i = 0; i < NMT; ++i)
                        Ah2[i] = *(const h8*)(whi + woff[i] + kwb);
                }
                const int kb  = kt * 32;
                const int kwb = kt * 512;
                h8 Bvh = *(const h8*)(vhi + boff + kb);
                h8 Bvl = *(const h8*)(vlo + boff + kb);
                h8 Bdh = *(const h8*)(dhi + boff + kb);
                h8 Bdd = *(const h8*)(ddh + boff + kb);
                __builtin_amdgcn_s_setprio(1);
#pragma unroll
                for (int i = 0; i < NMT; ++i) {
                    h8 Alo = *(const h8*)(wlo + woff[i] + kwb);
                    accva[i] = __builtin_amdgcn_mfma_f32_16x16x32_f16(Ah[i], Bvh, accva[i], 0, 0, 0);
                    accva[i] = __builtin_amdgcn_mfma_f32_16x16x32_f16(Ah[i], Bvl, accva[i], 0, 0, 0);
                    accva[i] = __builtin_amdgcn_mfma_f32_16x16x32_f16(Alo, Bvh, accva[i], 0, 0, 0);
                    accd[i]  = __builtin_amdgcn_mfma_f32_16x16x32_f16(Ah[i], Bdh, accd[i],  0, 0, 0);
                    accdd[i] = __builtin_amdgcn_mfma_f32_16x16x32_f16(Ah[i], Bdd, accdd[i], 0, 0, 0);
                }
                __builtin_amdgcn_s_setprio(0);
                if (kt + 1 < KT) {
#pragma unroll
                    for (int i = 0; i < NMT; ++i) Ah[i] = Ah2[i];
                }
            }
        }
    }
    __syncthreads();   // all reads of planes complete before in-place overwrite

    if (act) {
#pragma unroll
        for (int i = 0; i < NMT; ++i) {
            int mt = wv + NWACT * i;
            int o0 = mt * 16 + kg * 4;
            f4 bi = *(const f4*)(biasP + o0);
            h4 pvh, pvl, pdh, pdd;
#pragma unroll
            for (int r = 0; r < 4; ++r) {
                float zv;
                if constexpr (STG) zv = accva[i][r] + accvb[i][r] + bi[r];
                else               zv = accva[i][r] + bi[r];
                float zd  = accd[i][r];
                float zdd = accdd[i][r];
                float ov, od, odd;
                if constexpr (TANH) {
                    float t  = fast_tanh(zv);
                    float s2 = 1.0f - t * t;
                    ov  = t;
                    od  = s2 * zd;
                    odd = s2 * zdd - 2.0f * t * s2 * zd * zd;
                } else {
                    ov = zv; od = zd; odd = zdd;
                }
                Split sv = split16(ov);
                pvh[r] = sv.hi; pvl[r] = sv.lo;
                pdh[r] = (_Float16)od;
                pdd[r] = (_Float16)odd;
            }
            int off = colS * STR + o0;
            *(h4*)(vhi + off) = pvh;
            *(h4*)(vlo + off) = pvl;
            *(h4*)(dhi + off) = pdh;
            *(h4*)(ddh + off) = pdd;
        }
    }
    __syncthreads();
}

// ---------------- main fused kernel ----------------
__global__ __launch_bounds__(THREADS, 4) void pinn_mfma(
    const float* __restrict__ W0, const float* __restrict__ b0,
    const float* __restrict__ x,
    const _Float16* __restrict__ whi, const float* __restrict__ biasP,
    float* __restrict__ out)
{
    __shared__ __align__(16) _Float16 smem[4 * BS * STR];   // 66,560 B
    __shared__ float xs[BS];

    _Float16* vhi = smem + 0 * BS * STR;
    _Float16* vlo = smem + 1 * BS * STR;
    _Float16* dhi = smem + 2 * BS * STR;
    _Float16* ddh = smem + 3 * BS * STR;

    const int tid  = threadIdx.x;
    const int bid  = blockIdx.x;
    const int lane = tid & 63;
    const int wv   = tid >> 6;
    const _Float16* wlo = whi + SW;

    if (tid < BS) xs[tid] = x[bid * BS + tid];
    __syncthreads();

    // ---- layer 0: 1 -> 20, write padded-K (32) input planes ----
    {
        int s = tid >> 5;       // 0..15
        int k = tid & 31;       // 0..31
        float v0 = 0.f, v1 = 0.f, v2 = 0.f;
        if (k < 20) {
            float w  = W0[k];
            float z  = w * xs[s] + b0[k];
            float t  = fast_tanh(z);
            float s2 = 1.0f - t * t;
            v0 = t; v1 = s2 * w; v2 = -2.0f * t * s2 * w * w;
        }
        Split s0 = split16(v0);
        int off = s * STR + k;
        vhi[off] = s0.hi;           vlo[off] = s0.lo;
        dhi[off] = (_Float16)v1;    ddh[off] = (_Float16)v2;
    }
    __syncthreads();

    //          KP   MT NMT NWA FOUT
    layer_mfma< 32,  4, 1,  4,  50, true>(whi, wlo, C1, biasP + BP1, vhi, vlo, dhi, ddh, lane, wv);
    layer_mfma< 64, 14, 2,  7, 200, true>(whi, wlo, C2, biasP + BP2, vhi, vlo, dhi, ddh, lane, wv);
    layer_mfma<224, 32, 4,  8, 500, true>(whi, wlo, C3, biasP + BP3, vhi, vlo, dhi, ddh, lane, wv);
    layer_mfma<512, 14, 2,  7, 200, true>(whi, wlo, C4, biasP + BP4, vhi, vlo, dhi, ddh, lane, wv);

    // ---- layer 5: 200 -> 100 linear -> U, Uxx, F; then dual tail MFMA ----
    {
        constexpr int KT = 7;
        const int colS = lane & 15;
        const int kg   = lane >> 4;
        const bool act = (wv < 7);
        const int o0L5 = wv * 16 + kg * 4;
        f4 uo;                       // U kept in registers across the tail
        f4 ava = (f4){0.f,0.f,0.f,0.f}, avb = ava, ad = ava, add = ava;
        if (act) {
            const int boff = colS * STR + kg * 8;
            const unsigned w5off = (unsigned)(C5 + (wv * KT) * 512 + lane * 8);
            h8 Ah = *(const h8*)(whi + w5off);
            h8 Al = *(const h8*)(wlo + w5off);
            h8 Ah2, Al2;
#pragma unroll
            for (int kt = 0; kt < KT; ++kt) {
                if (kt + 1 < KT) {
                    const int kwb = (kt + 1) * 512;
                    Ah2 = *(const h8*)(whi + w5off + kwb);
                    Al2 = *(const h8*)(wlo + w5off + kwb);
                }
                const int kb = kt * 32;
                h8 Bvh = *(const h8*)(vhi + boff + kb);
                h8 Bvl = *(const h8*)(vlo + boff + kb);
                h8 Bdh = *(const h8*)(dhi + boff + kb);
                h8 Bdd = *(const h8*)(ddh + boff + kb);
                __builtin_amdgcn_s_setprio(1);
                ava = __builtin_amdgcn_mfma_f32_16x16x32_f16(Ah, Bvh, ava, 0, 0, 0);
                avb = __builtin_amdgcn_mfma_f32_16x16x32_f16(Ah, Bvl, avb, 0, 0, 0);
                avb = __builtin_amdgcn_mfma_f32_16x16x32_f16(Al, Bvh, avb, 0, 0, 0);
                ad  = __builtin_amdgcn_mfma_f32_16x16x32_f16(Ah, Bdh, ad,  0, 0, 0);
                add = __builtin_amdgcn_mfma_f32_16x16x32_f16(Ah, Bdd, add, 0, 0, 0);
                __builtin_amdgcn_s_setprio(0);
                if (kt + 1 < KT) { Ah = Ah2; Al = Al2; }
            }
        }
        __syncthreads();   // all plane reads done; vhi/vlo reused for split-F

        // epilogue: U (regs), F split into vhi/vlo (B-layout [s][k])
        h4 fh, fl;
        if (act && o0L5 < Q) {
            f4 bi = *(const f4*)(biasP + BP5 + o0L5);
            float xv = xs[colS];
            float xm = xv * xv - 1.0f;
#pragma unroll
            for (int r = 0; r < 4; ++r) {
                float gv  = ava[r] + avb[r] + bi[r];
                float gd  = ad[r];
                float gdd = add[r];
                float U   = -1.0f + xm * gv;
                float Uxx = 2.0f * gv + 4.0f * xv * gd + xm * gdd;
                float Fv  = 5.0f * U * U * U - 5.0f * U - 0.0005f * Uxx;
                uo[r] = U;
                Split sf = split16(Fv);
                fh[r] = sf.hi; fl[r] = sf.lo;
            }
            *(h4*)(vhi + colS * STR + o0L5) = fh;
            *(h4*)(vlo + colS * STR + o0L5) = fl;
        }
        // zero-pad k in [100,128) of the F planes (16 rows x 28 halves x 2)
        if (tid < 224) {
            int pl  = tid / 112;
            int u   = tid - pl * 112;
            int row = u / 7, c = u - row * 7;
            _Float16* P = pl ? vlo : vhi;
            *(h4*)(P + row * STR + 100 + c * 4) = (h4){0,0,0,0};
        }
        __syncthreads();

        // ---- dual tail MFMA: tile wv (A -> U0), tile 7+wv (A2 -> U1) ----
        f4 tva = (f4){0.f,0.f,0.f,0.f}, tvb = tva, t2a = tva, t2b = tva;
        if (act) {
            const int boff = colS * STR + kg * 8;
            const unsigned ao1 = (unsigned)(C6 + (wv * 4) * 512 + lane * 8);
            const unsigned ao2 = (unsigned)(C6 + ((7 + wv) * 4) * 512 + lane * 8);
#pragma unroll
            for (int kt = 0; kt < 4; ++kt) {
                const int kwb = kt * 512;
                h8 Bh  = *(const h8*)(vhi + boff + kt * 32);
                h8 Bl  = *(const h8*)(vlo + boff + kt * 32);
                h8 A1h = *(const h8*)(whi + ao1 + kwb);
                h8 A1l = *(const h8*)(wlo + ao1 + kwb);
                h8 A2h = *(const h8*)(whi + ao2 + kwb);
                h8 A2l = *(const h8*)(wlo + ao2 + kwb);
                __builtin_amdgcn_s_setprio(1);
                tva = __builtin_amdgcn_mfma_f32_16x16x32_f16(A1h, Bh, tva, 0, 0, 0);
                tvb = __builtin_amdgcn_mfma_f32_16x16x32_f16(A1h, Bl, tvb, 0, 0, 0);
                tvb = __builtin_amdgcn_mfma_f32_16x16x32_f16(A1l, Bh, tvb, 0, 0, 0);
                t2a = __builtin_amdgcn_mfma_f32_16x16x32_f16(A2h, Bh, t2a, 0, 0, 0);
                t2b = __builtin_amdgcn_mfma_f32_16x16x32_f16(A2h, Bl, t2b, 0, 0, 0);
                t2b = __builtin_amdgcn_mfma_f32_16x16x32_f16(A2l, Bh, t2b, 0, 0, 0);
                __builtin_amdgcn_s_setprio(0);
            }
        }

        // ---- final combine + store (regs only; no barrier needed) ----
        if (act && o0L5 < Q) {
            f4 u0, u1;
#pragma unroll
            for (int r = 0; r < 4; ++r) {
                u0[r] = uo[r] + DTC * (tva[r] + tvb[r]);
                u1[r] = uo[r] + DTC * (t2a[r] + t2b[r]);
            }
            int sg = bid * BS + colS;
            *(f4*)(out + sg * Q + o0L5) = u0;
            *(f4*)(out + NSAMP * Q + sg * Q + o0L5) = u1;
        }
    }
}

extern "C" void kernel_launch(void* const* d_in, const int* in_sizes, int n_in,
                              void* d_out, int out_size, void* d_ws, size_t ws_size,
                              hipStream_t stream) {
    const float* W0 = (const float*)d_in[0];
    const float* b0 = (const float*)d_in[1];
    const float* W1 = (const float*)d_in[2];
    const float* b1 = (const float*)d_in[3];
    const float* W2 = (const float*)d_in[4];
    const float* b2 = (const float*)d_in[5];
    const float* W3 = (const float*)d_in[6];
    const float* b3 = (const float*)d_in[7];
    const float* W4 = (const float*)d_in[8];
    const float* b4 = (const float*)d_in[9];
    const float* W5 = (const float*)d_in[10];
    const float* b5 = (const float*)d_in[11];
    const float* x  = (const float*)d_in[12];
    const float* A  = (const float*)d_in[13];
    const float* bv = (const float*)d_in[14];
    float* out = (float*)d_out;

    _Float16* whi = (_Float16*)d_ws;
    float* biasP  = (float*)((char*)d_ws + WS_BIAS_BYTE_OFF);

    prepass<<<(SW + BPTOT + 255) / 256, 256, 0, stream>>>(
        W1, b1, W2, b2, W3, b3, W4, b4, W5, b5, A, bv, whi, biasP);

    pinn_mfma<<<NSAMP / BS, THREADS, 0, stream>>>(
        W0, b0, x, whi, biasP, out);
}

// Round 13
// 223.729 us; speedup vs baseline: 1.3970x; 1.3970x over previous
//
#include <hip/hip_runtime.h>
#include <hip/hip_bf16.h>

// PINN fused forward+jvp^2 via PLAIN-fp16 MFMA.
// R22 = R19 structure (234.5us: BS=16, 512thr, 2 blocks/CU, STR=520,
// staged A-frags, setprio, MFMA tail via Aext=[A;bvec;0], no dead guards,
// full unroll) with the split-fp16 machinery REMOVED:
//   - v-channel is plain fp16 like d/dd already were (tolerance evidence:
//     absmax 0.5 passes; est. plain-fp16 error ~1e-2).
//   - 3 MFMAs per (mt,kt) instead of 5 (-40% matrix work).
//   - A-loads halve (no Alo); weight workspace halves (FETCH halves).
//   - 3 LDS planes (vh,dh,dd) = 49.9KB; B-reads 4->3 per kt.
//   - L3 now staged uniformly (1 A-load/frag fits the register budget).
//   - Tail: 1 MFMA/kt; cbv row-100 broadcast as in R19.
// R20/R21 lesson: scheduling levers are exhausted (reg-file-limited
// parallelism); this is the work-reduction lever.

#define NSAMP 65536
#define Q     100
#define DTC   0.8f
#define BS    16
#define THREADS 512
#define STR   520          // LDS plane stride (halves); MUST be mult of 8

typedef _Float16 h8 __attribute__((ext_vector_type(8)));
typedef _Float16 h4 __attribute__((ext_vector_type(4)));
typedef float    f4 __attribute__((ext_vector_type(4)));

// ---- packed fragment-ready weight geometry (halves) ----
// per layer: MT * KT * 512 halves (frag = 64 lanes x 8 halves)
// L1: MT=4,  KT=1  ->   2048
// L2: MT=14, KT=2  ->  14336
// L3: MT=32, KT=7  -> 114688
// L4: MT=14, KT=16 -> 114688
// L5: MT=7,  KT=7  ->  25088
// L6 (Aext=[A;bvec;0], 112x100): MT=7, KT=4 -> 14336
#define SW 285184
#define C1 0
#define C2 2048
#define C3 16384
#define C4 131072
#define C5 245760
#define C6 270848
#define BP1 0
#define BP2 64
#define BP3 288
#define BP4 800
#define BP5 1024
#define BPTOT 1136
#define WS_BIAS_BYTE_OFF (SW*2)

__device__ __forceinline__ float fast_tanh(float z) {
    float az = fabsf(z);
    float e  = __expf(-2.0f * az);
    float r  = __builtin_amdgcn_rcpf(1.0f + e);
    float t  = (1.0f - e) * r;
    return copysignf(t, z);
}

// ---------------- pre-pass: pad/PACK fp16 weights + biases + Aext into d_ws ----------------
__global__ __launch_bounds__(256) void prepass(
    const float* __restrict__ W1, const float* __restrict__ b1,
    const float* __restrict__ W2, const float* __restrict__ b2,
    const float* __restrict__ W3, const float* __restrict__ b3,
    const float* __restrict__ W4, const float* __restrict__ b4,
    const float* __restrict__ W5, const float* __restrict__ b5,
    const float* __restrict__ Amat, const float* __restrict__ bvec,
    _Float16* __restrict__ whi, float* __restrict__ biasP)
{
    int idx = blockIdx.x * 256 + threadIdx.x;
    if (idx < SW) {
        int base, KT, K, FOUT; const float* W; bool ext = false;
        if      (idx < C2) { base=C1; KT=1;  K=20;  FOUT=50;  W=W1; }
        else if (idx < C3) { base=C2; KT=2;  K=50;  FOUT=200; W=W2; }
        else if (idx < C4) { base=C3; KT=7;  K=200; FOUT=500; W=W3; }
        else if (idx < C5) { base=C4; KT=16; K=500; FOUT=200; W=W4; }
        else if (idx < C6) { base=C5; KT=7;  K=200; FOUT=100; W=W5; }
        else               { base=C6; KT=4;  K=100; FOUT=101; W=Amat; ext = true; }
        int r    = idx - base;
        int frag = r >> 9;
        int f    = r & 511;
        int lane = f >> 3;
        int e    = f & 7;
        int colS = lane & 15;
        int kg   = lane >> 4;
        int mt   = frag / KT;
        int kt   = frag - mt * KT;
        int o = mt * 16 + colS;
        int k = kt * 32 + kg * 8 + e;
        float v = 0.f;
        if (o < FOUT && k < K) {
            if (ext && o == 100) v = bvec[k];
            else                 v = W[o * K + k];
        }
        whi[idx] = (_Float16)v;
    } else if (idx < SW + BPTOT) {
        int b = idx - SW;
        const float* src; int FOUT; int o;
        if      (b < BP2)  { src=b1; FOUT=50;  o=b;        }
        else if (b < BP3)  { src=b2; FOUT=200; o=b-BP2;    }
        else if (b < BP4)  { src=b3; FOUT=500; o=b-BP3;    }
        else if (b < BP5)  { src=b4; FOUT=200; o=b-BP4;    }
        else               { src=b5; FOUT=100; o=b-BP5;    }
        biasP[b] = (o < FOUT) ? src[o] : 0.f;
    }
}

// ---------------- one MFMA layer (plain fp16) ----------------
// Planes (LDS, stride STR halves): vh, dh, dd.
// B-frag: lane l -> col = l&15 (sample), k0 = (l>>4)*8 + kt*32.
// A-frag: PACKED: base + (mt*KT + kt)*512 + lane*8  -> coalesced 1KB load.
// C/D: col(lane&15)=sample, row((lane>>4)*4+reg)=output neuron.
// All layers staged: Ah for kt+1 loaded while kt's MFMAs run.
// Epilogue: no FOUT guard (zero-padded weights make padded outputs 0).
template<int KP, int MTILES, int NMT, int NWACT, int FOUT, bool TANH>
__device__ __forceinline__ void layer_mfma(
    const _Float16* __restrict__ whi,
    int wcoff, const float* __restrict__ biasP,
    _Float16* vh, _Float16* dh, _Float16* dd,
    int lane, int wv)
{
    constexpr int KT = KP / 32;
    static_assert(MTILES == NMT * NWACT, "exact tiling expected");
    const int colS = lane & 15;
    const int kg   = lane >> 4;
    const bool act = (wv < NWACT);

    f4 accv[NMT], accd[NMT], accdd[NMT];

    if (act) {
#pragma unroll
        for (int i = 0; i < NMT; ++i) {
            accv[i]  = (f4){0.f, 0.f, 0.f, 0.f};
            accd[i]  = (f4){0.f, 0.f, 0.f, 0.f};
            accdd[i] = (f4){0.f, 0.f, 0.f, 0.f};
        }

        const int boff = colS * STR + kg * 8;

        unsigned woff[NMT];
#pragma unroll
        for (int i = 0; i < NMT; ++i)
            woff[i] = (unsigned)(wcoff + ((wv + NWACT * i) * KT) * 512 + lane * 8);

        h8 Ah[NMT], Ah2[NMT];
#pragma unroll
        for (int i = 0; i < NMT; ++i)
            Ah[i] = *(const h8*)(whi + woff[i]);
#pragma unroll
        for (int kt = 0; kt < KT; ++kt) {
            if (kt + 1 < KT) {
                const int kwb = (kt + 1) * 512;
#pragma unroll
                for (int i = 0; i < NMT; ++i)
                    Ah2[i] = *(const h8*)(whi + woff[i] + kwb);
            }
            const int kb = kt * 32;
            h8 Bv = *(const h8*)(vh + boff + kb);
            h8 Bd = *(const h8*)(dh + boff + kb);
            h8 Bc = *(const h8*)(dd + boff + kb);
            __builtin_amdgcn_s_setprio(1);
#pragma unroll
            for (int i = 0; i < NMT; ++i) {
                accv[i]  = __builtin_amdgcn_mfma_f32_16x16x32_f16(Ah[i], Bv, accv[i],  0, 0, 0);
                accd[i]  = __builtin_amdgcn_mfma_f32_16x16x32_f16(Ah[i], Bd, accd[i],  0, 0, 0);
                accdd[i] = __builtin_amdgcn_mfma_f32_16x16x32_f16(Ah[i], Bc, accdd[i], 0, 0, 0);
            }
            __builtin_amdgcn_s_setprio(0);
            if (kt + 1 < KT) {
#pragma unroll
                for (int i = 0; i < NMT; ++i) Ah[i] = Ah2[i];
            }
        }
    }
    __syncthreads();   // all reads of planes complete before in-place overwrite

    if (act) {
#pragma unroll
        for (int i = 0; i < NMT; ++i) {
            int mt = wv + NWACT * i;
            int o0 = mt * 16 + kg * 4;
            f4 bi = *(const f4*)(biasP + o0);
            h4 pv, pd, pc;
#pragma unroll
            for (int r = 0; r < 4; ++r) {
                float zv  = accv[i][r] + bi[r];
                float zd  = accd[i][r];
                float zdd = accdd[i][r];
                float ov, od, odd;
                if constexpr (TANH) {
                    float t  = fast_tanh(zv);
                    float s2 = 1.0f - t * t;
                    ov  = t;
                    od  = s2 * zd;
                    odd = s2 * zdd - 2.0f * t * s2 * zd * zd;
                } else {
                    ov = zv; od = zd; odd = zdd;
                }
                pv[r] = (_Float16)ov;
                pd[r] = (_Float16)od;
                pc[r] = (_Float16)odd;
            }
            int off = colS * STR + o0;
            *(h4*)(vh + off) = pv;
            *(h4*)(dh + off) = pd;
            *(h4*)(dd + off) = pc;
        }
    }
    __syncthreads();
}

// ---------------- main fused kernel ----------------
__global__ __launch_bounds__(THREADS, 4) void pinn_mfma(
    const float* __restrict__ W0, const float* __restrict__ b0,
    const float* __restrict__ x,
    const _Float16* __restrict__ whi, const float* __restrict__ biasP,
    float* __restrict__ out)
{
    __shared__ __align__(16) _Float16 smem[3 * BS * STR];   // 49,920 B
    __shared__ float xs[BS];
    __shared__ float cbv[BS];

    _Float16* vh = smem + 0 * BS * STR;
    _Float16* dh = smem + 1 * BS * STR;
    _Float16* dd = smem + 2 * BS * STR;

    const int tid  = threadIdx.x;
    const int bid  = blockIdx.x;
    const int lane = tid & 63;
    const int wv   = tid >> 6;

    if (tid < BS) xs[tid] = x[bid * BS + tid];
    __syncthreads();

    // ---- layer 0: 1 -> 20, write padded-K (32) input planes ----
    {
        int s = tid >> 5;       // 0..15
        int k = tid & 31;       // 0..31
        float v0 = 0.f, v1 = 0.f, v2 = 0.f;
        if (k < 20) {
            float w  = W0[k];
            float z  = w * xs[s] + b0[k];
            float t  = fast_tanh(z);
            float s2 = 1.0f - t * t;
            v0 = t; v1 = s2 * w; v2 = -2.0f * t * s2 * w * w;
        }
        int off = s * STR + k;
        vh[off] = (_Float16)v0;
        dh[off] = (_Float16)v1;
        dd[off] = (_Float16)v2;
    }
    __syncthreads();

    //          KP   MT NMT NWA FOUT
    layer_mfma< 32,  4, 1,  4,  50, true>(whi, C1, biasP + BP1, vh, dh, dd, lane, wv);
    layer_mfma< 64, 14, 2,  7, 200, true>(whi, C2, biasP + BP2, vh, dh, dd, lane, wv);
    layer_mfma<224, 32, 4,  8, 500, true>(whi, C3, biasP + BP3, vh, dh, dd, lane, wv);
    layer_mfma<512, 14, 2,  7, 200, true>(whi, C4, biasP + BP4, vh, dh, dd, lane, wv);

    // ---- layer 5: 200 -> 100 linear -> U, Uxx, F; then tail via MFMA ----
    {
        constexpr int KT = 7;
        const int colS = lane & 15;
        const int kg   = lane >> 4;
        const bool act = (wv < 7);
        float* Umf = (float*)dh;           // 16 x 104 f32 in dead dh plane
        const int o0L5 = wv * 16 + kg * 4;
        f4 av = (f4){0.f,0.f,0.f,0.f}, ad = av, add = av;
        if (act) {
            const int boff = colS * STR + kg * 8;
            const unsigned w5off = (unsigned)(C5 + (wv * KT) * 512 + lane * 8);
            h8 Ah = *(const h8*)(whi + w5off);
            h8 Ah2;
#pragma unroll
            for (int kt = 0; kt < KT; ++kt) {
                if (kt + 1 < KT)
                    Ah2 = *(const h8*)(whi + w5off + (kt + 1) * 512);
                const int kb = kt * 32;
                h8 Bv = *(const h8*)(vh + boff + kb);
                h8 Bd = *(const h8*)(dh + boff + kb);
                h8 Bc = *(const h8*)(dd + boff + kb);
                __builtin_amdgcn_s_setprio(1);
                av  = __builtin_amdgcn_mfma_f32_16x16x32_f16(Ah, Bv, av,  0, 0, 0);
                ad  = __builtin_amdgcn_mfma_f32_16x16x32_f16(Ah, Bd, ad,  0, 0, 0);
                add = __builtin_amdgcn_mfma_f32_16x16x32_f16(Ah, Bc, add, 0, 0, 0);
                __builtin_amdgcn_s_setprio(0);
                if (kt + 1 < KT) Ah = Ah2;
            }
        }
        __syncthreads();   // all plane reads done; vh reused for F, dh for U(f32)

        // epilogue: U, Uxx, F; F (fp16) into vh plane, U (f32) into Umf
        if (act && o0L5 < Q) {
            f4 bi = *(const f4*)(biasP + BP5 + o0L5);
            float xv = xs[colS];
            float xm = xv * xv - 1.0f;
            f4 uo; h4 fh;
#pragma unroll
            for (int r = 0; r < 4; ++r) {
                float gv  = av[r] + bi[r];
                float gd  = ad[r];
                float gdd = add[r];
                float U   = -1.0f + xm * gv;
                float Uxx = 2.0f * gv + 4.0f * xv * gd + xm * gdd;
                float Fv  = 5.0f * U * U * U - 5.0f * U - 0.0005f * Uxx;
                uo[r] = U;
                fh[r] = (_Float16)Fv;
            }
            *(f4*)(Umf + colS * 104 + o0L5) = uo;
            *(h4*)(vh + colS * STR + o0L5)  = fh;
        }
        // zero-pad k in [100,128) of the F plane (16 rows x 28 halves)
        if (tid < 112) {
            int row = tid / 7, c = tid - row * 7;
            *(h4*)(vh + row * STR + 100 + c * 4) = (h4){0,0,0,0};
        }
        __syncthreads();

        // ---- tail MFMA: [U0;cb] rows = Aext(112x100) @ F ----
        f4 tv = (f4){0.f,0.f,0.f,0.f};
        if (act) {
            const int boff = colS * STR + kg * 8;
            const unsigned aoff = (unsigned)(C6 + (wv * 4) * 512 + lane * 8);
            h8 Ah = *(const h8*)(whi + aoff);
            h8 Ah2;
#pragma unroll
            for (int kt = 0; kt < 4; ++kt) {
                if (kt < 3)
                    Ah2 = *(const h8*)(whi + aoff + (kt + 1) * 512);
                h8 Bh = *(const h8*)(vh + boff + kt * 32);
                __builtin_amdgcn_s_setprio(1);
                tv = __builtin_amdgcn_mfma_f32_16x16x32_f16(Ah, Bh, tv, 0, 0, 0);
                __builtin_amdgcn_s_setprio(0);
                if (kt < 3) Ah = Ah2;
            }
        }
        // row 100 (= F@bvec^T) lives at wv==6, kg==1, r==0; broadcast per sample
        if (wv == 6 && kg == 1) cbv[colS] = DTC * tv[0];
        __syncthreads();

        // ---- final combine + store ----
        if (act && o0L5 < Q) {
            float cbs = cbv[colS];
            f4 um = *(const f4*)(Umf + colS * 104 + o0L5);
            f4 u0, u1;
#pragma unroll
            for (int r = 0; r < 4; ++r) {
                u0[r] = um[r] + DTC * tv[r];
                u1[r] = u0[r] - cbs;
            }
            int sg = bid * BS + colS;
            *(f4*)(out + sg * Q + o0L5) = u0;
            *(f4*)(out + NSAMP * Q + sg * Q + o0L5) = u1;
        }
    }
}

extern "C" void kernel_launch(void* const* d_in, const int* in_sizes, int n_in,
                              void* d_out, int out_size, void* d_ws, size_t ws_size,
                              hipStream_t stream) {
    const float* W0 = (const float*)d_in[0];
    const float* b0 = (const float*)d_in[1];
    const float* W1 = (const float*)d_in[2];
    const float* b1 = (const float*)d_in[3];
    const float* W2 = (const float*)d_in[4];
    const float* b2 = (const float*)d_in[5];
    const float* W3 = (const float*)d_in[6];
    const float* b3 = (const float*)d_in[7];
    const float* W4 = (const float*)d_in[8];
    const float* b4 = (const float*)d_in[9];
    const float* W5 = (const float*)d_in[10];
    const float* b5 = (const float*)d_in[11];
    const float* x  = (const float*)d_in[12];
    const float* A  = (const float*)d_in[13];
    const float* bv = (const float*)d_in[14];
    float* out = (float*)d_out;

    _Float16* whi = (_Float16*)d_ws;
    float* biasP  = (float*)((char*)d_ws + WS_BIAS_BYTE_OFF);

    prepass<<<(SW + BPTOT + 255) / 256, 256, 0, stream>>>(
        W1, b1, W2, b2, W3, b3, W4, b4, W5, b5, A, bv, whi, biasP);

    pinn_mfma<<<NSAMP / BS, THREADS, 0, stream>>>(
        W0, b0, x, whi, biasP, out);
}